// Round 4
// baseline (535.028 us; speedup 1.0000x reference)
//
#include <hip/hip_runtime.h>
#include <hip/hip_bf16.h>

// LinkPredictorGAT: out[e] = relu(concat(z[src[e]], z[dst[e]]) @ W1 + b1) @ W2 + b2
// R3: barrier-free, LDS-free main loop. B^T (128 KB, L2-resident) read directly
// from global per k-step; A gathered from bf16 z copy with depth-1 prefetch.
// Rationale: R2 counters showed MfmaUtil 20% / VALUBusy 12% / Occ 21% — barrier-
// correlated latency stalls, not pipe saturation. Decouple the waves.

typedef __attribute__((ext_vector_type(4))) float floatx4;
typedef __attribute__((ext_vector_type(8))) short short8;

__device__ __forceinline__ unsigned short bf16rne(float x) {
    unsigned int u = __float_as_uint(x);
    u += 0x7fffu + ((u >> 16) & 1u);
    return (unsigned short)(u >> 16);
}

// ---- convert z (fp32 -> bf16), float4 per thread ----
__global__ void cvt_z(const float* __restrict__ z, unsigned short* __restrict__ zb, int n4) {
    int i = blockIdx.x * blockDim.x + threadIdx.x;
    if (i < n4) {
        float4 f = ((const float4*)z)[i];
        ushort4 u;
        u.x = bf16rne(f.x); u.y = bf16rne(f.y);
        u.z = bf16rne(f.z); u.w = bf16rne(f.w);
        ((ushort4*)zb)[i] = u;
    }
}

// ---- convert W1 [512][128] fp32 -> BT [128][512] bf16 (transposed), coalesced stores ----
__global__ void cvt_w1(const float* __restrict__ W1, unsigned short* __restrict__ BT) {
    int g = blockIdx.x * blockDim.x + threadIdx.x;   // 0..65535
    int n = g >> 9, k = g & 511;                     // consecutive threads -> consecutive k
    BT[g] = bf16rne(W1[k * 128 + n]);                // BT[n][k] = W1[k][n]
}

// ---- fused gather + GEMM(512x128) + bias + relu + GEMV(W2), no LDS, no barriers ----
// block = 256 threads (4 waves). Wave tile: 64 edges x 128 cols (mf=4, nf=8).
// acc = 128 VGPRs -> 2 waves/SIMD; latency hidden by 8 free-running waves/CU + prefetch.
template <bool ABF16>
__global__ __launch_bounds__(256, 2)
void fused_mlp(const float* __restrict__ zf, const unsigned short* __restrict__ zb,
               const int* __restrict__ eli, int E, int nnodes,
               const unsigned short* __restrict__ BT,
               const float* __restrict__ b1, const float* __restrict__ W2,
               const float* __restrict__ b2, float* __restrict__ out)
{
    const int t = threadIdx.x;
    const int wid = t >> 6;
    const int lane = t & 63;
    const int l15 = lane & 15;
    const int quad = lane >> 4;
    const int m0 = blockIdx.x * 256 + wid * 64;      // this wave's first edge

    // byte offsets of this lane's 4 src rows and 4 dst rows in zb (bf16 row = 512 B)
    unsigned offs[4], offd[4];
#pragma unroll
    for (int mf = 0; mf < 4; ++mf) {
        int e = m0 + mf * 16 + l15;
        e = e < E ? e : E - 1;                       // clamp tail (stores masked later)
        int s = eli[e];
        int d = eli[E + e];
        s = s < 0 ? 0 : (s >= nnodes ? nnodes - 1 : s);
        d = d < 0 ? 0 : (d >= nnodes ? nnodes - 1 : d);
        offs[mf] = (unsigned)s * 512u;
        offd[mf] = (unsigned)d * 512u;
    }
    const char* zbb = (const char*)(ABF16 ? (const void*)zb : (const void*)zf);

    // epilogue constants: this lane's 8 columns
    float b1v[8], w2v[8];
#pragma unroll
    for (int nf = 0; nf < 8; ++nf) {
        int c = nf * 16 + l15;
        b1v[nf] = b1[c];
        w2v[nf] = W2[c];
    }

    // B fragment base for this lane: BT[(nf*16+l15)][ks*32 + quad*8]
    const unsigned short* bp = BT + l15 * 512 + quad * 8;

    floatx4 acc[4][8];
#pragma unroll
    for (int mf = 0; mf < 4; ++mf)
#pragma unroll
        for (int nf = 0; nf < 8; ++nf)
            acc[mf][nf] = (floatx4){0.f, 0.f, 0.f, 0.f};

    // A-fragment loader: ks in [0,16), rows from src half (ks<8) or dst half
    auto load_a = [&](int ks, short8* dst) {
        const unsigned* off = (ks < 8) ? offs : offd;
        if constexpr (ABF16) {
            const int cbytes = (ks & 7) * 64 + quad * 16;   // col byte offset in bf16 row
#pragma unroll
            for (int mf = 0; mf < 4; ++mf)
                dst[mf] = *(const short8*)(zbb + (size_t)off[mf] + cbytes);
        } else {
            const int cbytes = (ks & 7) * 128 + quad * 32;  // fp32 row = 1024 B
#pragma unroll
            for (int mf = 0; mf < 4; ++mf) {
                const float* pf = (const float*)(zbb + (size_t)off[mf] * 2 + cbytes);
                float4 f0 = *(const float4*)pf;
                float4 f1 = *(const float4*)(pf + 4);
                short8 av;
                av[0] = (short)bf16rne(f0.x); av[1] = (short)bf16rne(f0.y);
                av[2] = (short)bf16rne(f0.z); av[3] = (short)bf16rne(f0.w);
                av[4] = (short)bf16rne(f1.x); av[5] = (short)bf16rne(f1.y);
                av[6] = (short)bf16rne(f1.z); av[7] = (short)bf16rne(f1.w);
                dst[mf] = av;
            }
        }
    };

    short8 a_cur[4], a_nxt[4];
    load_a(0, a_cur);

#pragma unroll
    for (int ks = 0; ks < 16; ++ks) {
        if (ks + 1 < 16) load_a(ks + 1, a_nxt);      // depth-1 prefetch (issues first)

        short8 bfr[8];
#pragma unroll
        for (int nf = 0; nf < 8; ++nf)
            bfr[nf] = *(const short8*)(bp + nf * 8192 + ks * 32);

#pragma unroll
        for (int nf = 0; nf < 8; ++nf)
#pragma unroll
            for (int mf = 0; mf < 4; ++mf)
                acc[mf][nf] = __builtin_amdgcn_mfma_f32_16x16x32_bf16(
                    a_cur[mf], bfr[nf], acc[mf][nf], 0, 0, 0);

#pragma unroll
        for (int mf = 0; mf < 4; ++mf) a_cur[mf] = a_nxt[mf];
    }

    // epilogue: h = relu(acc + b1); s = h . W2 ; reduce over 128 cols
    // C/D layout: col = lane&15 (+16*nf), row = quad*4 + r (+16*mf)
    const float b2s = b2[0];
#pragma unroll
    for (int mf = 0; mf < 4; ++mf) {
#pragma unroll
        for (int r = 0; r < 4; ++r) {
            float s = 0.f;
#pragma unroll
            for (int nf = 0; nf < 8; ++nf) {
                float v = acc[mf][nf][r] + b1v[nf];
                v = v > 0.f ? v : 0.f;
                s = fmaf(v, w2v[nf], s);
            }
            s += __shfl_xor(s, 1);
            s += __shfl_xor(s, 2);
            s += __shfl_xor(s, 4);
            s += __shfl_xor(s, 8);
            if (l15 == 0) {
                int e = m0 + mf * 16 + quad * 4 + r;
                if (e < E) out[e] = s + b2s;
            }
        }
    }
}

// ---- emergency fallback (tiny ws): one block per edge, fp32 vector ----
__global__ void naive_edge(const float* __restrict__ z, const int* __restrict__ eli,
                           int E, int nnodes,
                           const float* __restrict__ W1, const float* __restrict__ b1,
                           const float* __restrict__ W2, const float* __restrict__ b2,
                           float* __restrict__ out)
{
    __shared__ float red[2];
    int e = blockIdx.x;
    int j = threadIdx.x;                 // 0..127 -> hidden unit
    int s = eli[e], d = eli[E + e];
    s = s < 0 ? 0 : (s >= nnodes ? nnodes - 1 : s);
    d = d < 0 ? 0 : (d >= nnodes ? nnodes - 1 : d);
    const float* zs = z + (long long)s * 256;
    const float* zd = z + (long long)d * 256;
    float h = b1[j];
    for (int i = 0; i < 256; ++i) h = fmaf(zs[i], W1[i * 128 + j], h);
    for (int i = 0; i < 256; ++i) h = fmaf(zd[i], W1[(256 + i) * 128 + j], h);
    h = h > 0.f ? h : 0.f;
    float v = h * W2[j];
    v += __shfl_xor(v, 1);  v += __shfl_xor(v, 2);  v += __shfl_xor(v, 4);
    v += __shfl_xor(v, 8);  v += __shfl_xor(v, 16); v += __shfl_xor(v, 32);
    if ((threadIdx.x & 63) == 0) red[threadIdx.x >> 6] = v;
    __syncthreads();
    if (threadIdx.x == 0) out[e] = red[0] + red[1] + b2[0];
}

extern "C" void kernel_launch(void* const* d_in, const int* in_sizes, int n_in,
                              void* d_out, int out_size, void* d_ws, size_t ws_size,
                              hipStream_t stream) {
    const float* z   = (const float*)d_in[0];
    const int*   eli = (const int*)d_in[1];      // int64 in reference -> int32 on device
    const float* W1  = (const float*)d_in[2];
    const float* b1  = (const float*)d_in[3];
    const float* W2  = (const float*)d_in[4];
    const float* b2  = (const float*)d_in[5];
    float*       out = (float*)d_out;

    const int E      = in_sizes[1] / 2;
    const int nnodes = in_sizes[0] / 256;

    const size_t ZB  = (size_t)nnodes * 256 * 2;   // z in bf16
    const size_t BTB = (size_t)512 * 128 * 2;      // W1^T in bf16

    const int grid_main = (E + 255) / 256;

    if (ws_size >= ZB + BTB) {
        unsigned short* zb = (unsigned short*)d_ws;
        unsigned short* BT = (unsigned short*)((char*)d_ws + ZB);
        int n4 = nnodes * 64;  // float4 count
        cvt_z<<<(n4 + 255) / 256, 256, 0, stream>>>(z, zb, n4);
        cvt_w1<<<256, 256, 0, stream>>>(W1, BT);
        fused_mlp<true><<<grid_main, 256, 0, stream>>>(nullptr, zb, eli, E, nnodes, BT, b1, W2, b2, out);
    } else if (ws_size >= BTB) {
        unsigned short* BT = (unsigned short*)d_ws;
        cvt_w1<<<256, 256, 0, stream>>>(W1, BT);
        fused_mlp<false><<<grid_main, 256, 0, stream>>>(z, nullptr, eli, E, nnodes, BT, b1, W2, b2, out);
    } else {
        naive_edge<<<E, 128, 0, stream>>>(z, eli, E, nnodes, W1, b1, W2, b2, out);
    }
}